// Round 1
// baseline (530.233 us; speedup 1.0000x reference)
//
#include <hip/hip_runtime.h>
#include <stdint.h>

#define B_ 8
#define T_ 4096
#define D_ 1024
#define H_ 1024
#define M_ (B_*T_)   /* 32768 */
#define K_ D_
#define N_ H_
#define TC 64
#define NC (T_/TC)   /* 64 */

typedef short short8 __attribute__((ext_vector_type(8)));
typedef float f32x4 __attribute__((ext_vector_type(4)));

__device__ __forceinline__ float bf2f(unsigned short u) {
    union { unsigned int i; float f; } x; x.i = ((unsigned int)u) << 16; return x.f;
}
__device__ __forceinline__ unsigned short f2bf(float f) {
    union { float f; unsigned int i; } x; x.f = f;
    unsigned int u = x.i;
    unsigned int r = u + 0x7fffu + ((u >> 16) & 1u);
    return (unsigned short)(r >> 16);
}
__device__ __forceinline__ void gld_lds16(const unsigned short* g, unsigned short* l) {
    __builtin_amdgcn_global_load_lds(
        (const __attribute__((address_space(1))) void*)(const void*)g,
        (__attribute__((address_space(3))) void*)(void*)l, 16, 0, 0);
}
__device__ __forceinline__ float gfun(float x) {
    return x >= 0.f ? x + 0.5f : 1.f / (1.f + __expf(-x));
}

// ---------------- fp32 -> bf16 convert (x, W_z, W_h) ----------------
__global__ void cvt_kernel(const float* __restrict__ src, unsigned short* __restrict__ dst, int n4) {
    int i = blockIdx.x * blockDim.x + threadIdx.x;
    const int stride = gridDim.x * blockDim.x;
    for (; i < n4; i += stride) {
        float4 v = ((const float4*)src)[i];
        ushort4 o;
        o.x = f2bf(v.x); o.y = f2bf(v.y); o.z = f2bf(v.z); o.w = f2bf(v.w);
        ((ushort4*)dst)[i] = o;
    }
}

// ---------------- bf16 MFMA GEMM: K = X(bf16)[M,K] * W^T(bf16)[N,K] + bias ----------------
// 128x128 tile, BK=32, 4 waves (2x2), 4x4 16x16x32 MFMAs/wave, global_load_lds width 16.
// blockIdx.z selects (W_z,b_z,KzOut) vs (W_h,b_h,KhOut).
__global__ __launch_bounds__(256) void gemm_kernel(
    const unsigned short* __restrict__ Xb,
    const unsigned short* __restrict__ Wzb,
    const unsigned short* __restrict__ Whb,
    const float* __restrict__ bz, const float* __restrict__ bh,
    unsigned short* __restrict__ KzOut, unsigned short* __restrict__ KhOut)
{
    __shared__ __align__(16) unsigned short lds_a[128 * 32];
    __shared__ __align__(16) unsigned short lds_b[128 * 32];

    const int bm = blockIdx.x;
    const int bn = blockIdx.y;
    const int mat = blockIdx.z;
    const unsigned short* Wb = mat ? Whb : Wzb;
    const float* bias = mat ? bh : bz;
    unsigned short* Out = mat ? KhOut : KzOut;

    const int tid = threadIdx.x;
    const int w = tid >> 6, lane = tid & 63;
    const int wm = w >> 1, wn = w & 1;

    f32x4 acc[4][4];
#pragma unroll
    for (int i = 0; i < 4; i++)
#pragma unroll
        for (int j = 0; j < 4; j++) acc[i][j] = (f32x4){0.f, 0.f, 0.f, 0.f};

    // staging: inst i of wave w covers rows (w*2+i)*16 + lane/4, k-chunk (lane&3)*8
    const int kc = (lane & 3) * 8;
    const unsigned short* gA0 = Xb + (size_t)(bm * 128 + (w * 2 + 0) * 16 + (lane >> 2)) * K_ + kc;
    const unsigned short* gA1 = Xb + (size_t)(bm * 128 + (w * 2 + 1) * 16 + (lane >> 2)) * K_ + kc;
    const unsigned short* gB0 = Wb + (size_t)(bn * 128 + (w * 2 + 0) * 16 + (lane >> 2)) * K_ + kc;
    const unsigned short* gB1 = Wb + (size_t)(bn * 128 + (w * 2 + 1) * 16 + (lane >> 2)) * K_ + kc;
    unsigned short* la0 = &lds_a[(w * 2 + 0) * 512];
    unsigned short* la1 = &lds_a[(w * 2 + 1) * 512];
    unsigned short* lb0 = &lds_b[(w * 2 + 0) * 512];
    unsigned short* lb1 = &lds_b[(w * 2 + 1) * 512];

    // fragment read base: A[m = lane&15][k = (lane>>4)*8 + j]
    const int koff = (lane >> 4) * 8;
    const unsigned short* ra = &lds_a[(wm * 64 + (lane & 15)) * 32 + koff];
    const unsigned short* rb = &lds_b[(wn * 64 + (lane & 15)) * 32 + koff];

    for (int k0 = 0; k0 < K_; k0 += 32) {
        __syncthreads();   // prior iter ds_reads done before overwrite
        gld_lds16(gA0 + k0, la0);
        gld_lds16(gA1 + k0, la1);
        gld_lds16(gB0 + k0, lb0);
        gld_lds16(gB1 + k0, lb1);
        __syncthreads();   // drains vmcnt before ds_read

        short8 af[4], bfr[4];
#pragma unroll
        for (int im = 0; im < 4; im++) af[im] = *(const short8*)(ra + im * 16 * 32);
#pragma unroll
        for (int in = 0; in < 4; in++) bfr[in] = *(const short8*)(rb + in * 16 * 32);
#pragma unroll
        for (int im = 0; im < 4; im++)
#pragma unroll
            for (int in = 0; in < 4; in++)
                acc[im][in] = __builtin_amdgcn_mfma_f32_16x16x32_bf16(af[im], bfr[in], acc[im][in], 0, 0, 0);
    }

    // epilogue: C/D map col=lane&15, row=(lane>>4)*4+r ; add bias, store bf16
#pragma unroll
    for (int in = 0; in < 4; in++) {
        const int col = bn * 128 + wn * 64 + in * 16 + (lane & 15);
        const float bb = bias[col];
#pragma unroll
        for (int im = 0; im < 4; im++) {
            const int row0 = bm * 128 + wm * 64 + im * 16 + (lane >> 4) * 4;
#pragma unroll
            for (int r = 0; r < 4; r++) {
                Out[(size_t)(row0 + r) * N_ + col] = f2bf(acc[im][in][r] + bb);
            }
        }
    }
}

// ---------------- scan A: per-chunk affine aggregates (F = prod f, V) ----------------
__global__ __launch_bounds__(256) void scanA_kernel(const unsigned short* __restrict__ Kz,
                                                    const unsigned short* __restrict__ Kh,
                                                    float* __restrict__ Fc, float* __restrict__ Vc)
{
    const int c = blockIdx.x, b = blockIdx.y;
    const int h = threadIdx.x * 4;
    size_t base = ((size_t)(b * T_ + c * TC)) * H_ + h;
    float F[4] = {1.f, 1.f, 1.f, 1.f}, V[4] = {0.f, 0.f, 0.f, 0.f};
    for (int t = 0; t < TC; t++) {
        ushort4 kz4 = *(const ushort4*)(Kz + base);
        ushort4 kh4 = *(const ushort4*)(Kh + base);
        base += H_;
        float kzf[4] = {bf2f(kz4.x), bf2f(kz4.y), bf2f(kz4.z), bf2f(kz4.w)};
        float khf[4] = {bf2f(kh4.x), bf2f(kh4.y), bf2f(kh4.z), bf2f(kh4.w)};
#pragma unroll
        for (int j = 0; j < 4; j++) {
            float f = 1.f / (1.f + __expf(kzf[j]));   // 1 - sigmoid(kz)
            float v = (1.f - f) * gfun(khf[j]);       // sigmoid(kz)*g(kh)
            V[j] = f * V[j] + v;
            F[j] *= f;
        }
    }
    size_t o = ((size_t)(b * NC + c)) * H_ + h;
    *(float4*)(Fc + o) = make_float4(F[0], F[1], F[2], F[3]);
    *(float4*)(Vc + o) = make_float4(V[0], V[1], V[2], V[3]);
}

// ---------------- scan B: serial scan over chunk aggregates; writes t=0 row ----------------
__global__ __launch_bounds__(256) void scanB_kernel(const float* __restrict__ h0,
                                                    const float* __restrict__ Fc,
                                                    const float* __restrict__ Vc,
                                                    float* __restrict__ Carry,
                                                    float* __restrict__ Out)
{
    const int b = blockIdx.x;
    const int h = threadIdx.x * 4;
    float cy[4];
#pragma unroll
    for (int j = 0; j < 4; j++) cy[j] = gfun(h0[(size_t)b * H_ + h + j]);
    *(float4*)(Out + (size_t)b * (T_ + 1) * H_ + h) = make_float4(cy[0], cy[1], cy[2], cy[3]);
    for (int c = 0; c < NC; c++) {
        size_t o = ((size_t)(b * NC + c)) * H_ + h;
        *(float4*)(Carry + o) = make_float4(cy[0], cy[1], cy[2], cy[3]);
        float4 F4 = *(const float4*)(Fc + o);
        float4 V4 = *(const float4*)(Vc + o);
        cy[0] = F4.x * cy[0] + V4.x;
        cy[1] = F4.y * cy[1] + V4.y;
        cy[2] = F4.z * cy[2] + V4.z;
        cy[3] = F4.w * cy[3] + V4.w;
    }
}

// ---------------- scan C: replay chunks with incoming carry, write outputs ----------------
__global__ __launch_bounds__(256) void scanC_kernel(const unsigned short* __restrict__ Kz,
                                                    const unsigned short* __restrict__ Kh,
                                                    const float* __restrict__ Carry,
                                                    float* __restrict__ Out)
{
    const int c = blockIdx.x, b = blockIdx.y;
    const int h = threadIdx.x * 4;
    float cy[4];
    {
        float4 c4 = *(const float4*)(Carry + ((size_t)(b * NC + c)) * H_ + h);
        cy[0] = c4.x; cy[1] = c4.y; cy[2] = c4.z; cy[3] = c4.w;
    }
    size_t base = ((size_t)(b * T_ + c * TC)) * H_ + h;
    size_t ob = ((size_t)(b * (T_ + 1) + c * TC + 1)) * H_ + h;
    for (int t = 0; t < TC; t++) {
        ushort4 kz4 = *(const ushort4*)(Kz + base);
        ushort4 kh4 = *(const ushort4*)(Kh + base);
        base += H_;
        float kzf[4] = {bf2f(kz4.x), bf2f(kz4.y), bf2f(kz4.z), bf2f(kz4.w)};
        float khf[4] = {bf2f(kh4.x), bf2f(kh4.y), bf2f(kh4.z), bf2f(kh4.w)};
#pragma unroll
        for (int j = 0; j < 4; j++) {
            float f = 1.f / (1.f + __expf(kzf[j]));
            float v = (1.f - f) * gfun(khf[j]);
            cy[j] = f * cy[j] + v;
        }
        *(float4*)(Out + ob) = make_float4(cy[0], cy[1], cy[2], cy[3]);
        ob += H_;
    }
}

extern "C" void kernel_launch(void* const* d_in, const int* in_sizes, int n_in,
                              void* d_out, int out_size, void* d_ws, size_t ws_size,
                              hipStream_t stream)
{
    const float* x  = (const float*)d_in[0];
    const float* h0 = (const float*)d_in[1];
    const float* Wz = (const float*)d_in[2];
    const float* bz = (const float*)d_in[3];
    const float* Wh = (const float*)d_in[4];
    const float* bh = (const float*)d_in[5];
    float* out = (float*)d_out;

    char* ws = (char*)d_ws;
    unsigned short* xb  = (unsigned short*)ws; ws += (size_t)M_ * K_ * 2;   // 64 MiB
    unsigned short* wzb = (unsigned short*)ws; ws += (size_t)N_ * K_ * 2;   // 2 MiB
    unsigned short* whb = (unsigned short*)ws; ws += (size_t)N_ * K_ * 2;   // 2 MiB
    unsigned short* kz  = (unsigned short*)ws; ws += (size_t)M_ * N_ * 2;   // 64 MiB
    unsigned short* kh  = (unsigned short*)ws; ws += (size_t)M_ * N_ * 2;   // 64 MiB
    float* Fc    = (float*)ws; ws += (size_t)B_ * NC * H_ * 4;              // 2 MiB
    float* Vc    = (float*)ws; ws += (size_t)B_ * NC * H_ * 4;              // 2 MiB
    float* Carry = (float*)ws; ws += (size_t)B_ * NC * H_ * 4;              // 2 MiB

    cvt_kernel<<<2048, 256, 0, stream>>>(x, xb, M_ * K_ / 4);
    cvt_kernel<<<256, 256, 0, stream>>>(Wz, wzb, N_ * K_ / 4);
    cvt_kernel<<<256, 256, 0, stream>>>(Wh, whb, N_ * K_ / 4);

    dim3 gg(M_ / 128, N_ / 128, 2);
    gemm_kernel<<<gg, 256, 0, stream>>>(xb, wzb, whb, bz, bh, kz, kh);

    scanA_kernel<<<dim3(NC, B_), 256, 0, stream>>>(kz, kh, Fc, Vc);
    scanB_kernel<<<B_, 256, 0, stream>>>(h0, Fc, Vc, Carry, out);
    scanC_kernel<<<dim3(NC, B_), 256, 0, stream>>>(kz, kh, Carry, out);
}